// Round 2
// 621.207 us; speedup vs baseline: 1.1991x; 1.1991x over previous
//
#include <hip/hip_runtime.h>
#include <hip/hip_bf16.h>

// ============================================================================
// UpConvsample2d via bf16 MFMA.
//
// Math (verified in round 1):
//   W1[c,o,a,b] = w[((c*256+o)*3+a)*3+b]
//   y1 parity planes p=(h'&1)*2+(w'&1), each 64x64 per (n,o):
//     ph=0 row taps: (r=i-1,a=2),(r=i,a=0)   ph=1: (r=i,a=1)   (cols same)
//   out = 3x3 FIR {0.4,1.2,0.4}^2 over y1 with top/left pad 2, crop 128x128.
//
// Phases:
//   1. pack x -> xp[n][65][65][512] bf16 (padded channel-last), w -> wp[ab][o][c]
//   2. mfma_conv: per parity, sum over taps of GEMM (M=spatial, N=o, K=c)
//      128x128 tile, 4 waves x (64x64), 16x16x32 bf16 MFMA, global_load_lds(16B)
//   3. fir_kernel: per (n,o) plane, stage 4 parity planes in LDS (short8
//      coalesced), each thread computes a quad-pair via 4B word reads,
//      float4 stores. (round 2: vectorized — old fir_quad was scalar-bf16.)
// ============================================================================

typedef __attribute__((ext_vector_type(8))) short short8;
typedef __attribute__((ext_vector_type(4))) float float4v;

#define XP_ELEMS ((size_t)16 * 65 * 65 * 512)   // 34,611,200
#define WP_ELEMS ((size_t)9 * 256 * 512)        // 1,179,648
#define YP_ELEMS ((size_t)4 * 16 * 256 * 4096)  // 67,108,864

__device__ __forceinline__ void gl_lds16(const __hip_bfloat16* g, __hip_bfloat16* l) {
    __builtin_amdgcn_global_load_lds(
        (const __attribute__((address_space(1))) void*)g,
        (__attribute__((address_space(3))) void*)l, 16, 0, 0);
}

// --------------------------------------------------------------- pack / pad -
__global__ __launch_bounds__(256) void zero_pad_kernel(__hip_bfloat16* __restrict__ xp) {
    int idx = blockIdx.x * 256 + (int)threadIdx.x;  // 16*65*512
    if (idx >= 16 * 65 * 512) return;
    int c = idx & 511;
    int t = (idx >> 9) % 65;
    int n = idx / (65 * 512);
    __hip_bfloat16 z = __float2bfloat16(0.f);
    xp[(((size_t)(n * 65) + 0) * 65 + t) * 512 + c] = z;   // pad row 0
    xp[(((size_t)(n * 65) + t) * 65 + 0) * 512 + c] = z;   // pad col 0
}

__global__ __launch_bounds__(256) void pack_w_kernel(
    const float* __restrict__ w, __hip_bfloat16* __restrict__ wp) {
    int idx = blockIdx.x * 256 + (int)threadIdx.x;  // 9*256*512
    int c  = idx & 511;
    int o  = (idx >> 9) & 255;
    int ab = idx >> 17;                  // 0..8
    int a = ab / 3, b = ab % 3;
    wp[idx] = __float2bfloat16(w[((size_t)(c * 256 + o) * 3 + a) * 3 + b]);
}

__global__ __launch_bounds__(256) void pack_x_kernel(
    const float* __restrict__ x, __hip_bfloat16* __restrict__ xp) {
    int i = blockIdx.x;       // 0..63
    int n = blockIdx.y;       // 0..15
    int tid = (int)threadIdx.x;
    __shared__ float tile[64][65];
    for (int c0 = 0; c0 < 512; c0 += 64) {
        __syncthreads();
#pragma unroll
        for (int rr = 0; rr < 16; rr++) {
            int cl = (tid >> 6) * 16 + rr;
            int j = tid & 63;
            tile[cl][j] = x[(((size_t)(n * 512 + c0 + cl) * 64) + i) * 64 + j];
        }
        __syncthreads();
        // write phase: 512 tasks = 64 j x 8 channel-groups of 8; ushort8 stores
#pragma unroll
        for (int pass = 0; pass < 2; pass++) {
            int task = pass * 256 + tid;
            int j  = task >> 3;          // 0..63
            int cg = task & 7;           // channel group of 8
            union { short8 v; unsigned short h[8]; } u;
#pragma unroll
            for (int r = 0; r < 8; r++) {
                __hip_bfloat16 b = __float2bfloat16(tile[cg * 8 + r][j]);
                u.h[r] = *(unsigned short*)&b;
            }
            *(short8*)(xp + (((size_t)(n * 65) + i + 1) * 65 + (j + 1)) * 512 +
                       c0 + cg * 8) = u.v;
        }
    }
}

// ---------------------------------------------------------------- mfma conv -
// grid: (2 N-tiles, 512 M-tiles, 4 parities), block 256 (4 waves)
__global__ __launch_bounds__(256) void mfma_conv_kernel(
    const __hip_bfloat16* __restrict__ xp, const __hip_bfloat16* __restrict__ wp,
    __hip_bfloat16* __restrict__ yp) {
    const int p  = blockIdx.z, ph = p >> 1, pw = p & 1;
    const int o0 = blockIdx.x * 128;
    const int mt = blockIdx.y;
    const int n  = mt >> 5;
    const int i0 = (mt & 31) << 1;      // block covers rows i0, i0+1
    const int tid  = (int)threadIdx.x;
    const int wave = tid >> 6, lane = tid & 63;
    const int wm = wave & 1, wn = wave >> 1;
    const int lrow = lane & 15, quad = lane >> 4;
    const int m0j   = wave * 16 + (lane >> 2);   // A/B tile row this lane stages
    const int klane = (lane & 3) * 8;            // k element offset this lane stages

    __shared__ __align__(16) __hip_bfloat16 lA[128 * 32];
    __shared__ __align__(16) __hip_bfloat16 lB[128 * 32];

    float4v acc[4][4];
#pragma unroll
    for (int fm = 0; fm < 4; fm++)
#pragma unroll
        for (int fn = 0; fn < 4; fn++) acc[fm][fn] = (float4v)0.f;

    __hip_bfloat16* la0 = lA + wave * 512;          // e=0 rows (di=0)
    __hip_bfloat16* la1 = lA + 2048 + wave * 512;   // e=1 rows (di=1)
    __hip_bfloat16* lb0 = lB + wave * 512;
    __hip_bfloat16* lb1 = lB + 2048 + wave * 512;

    const int nrt = ph ? 1 : 2, nct = pw ? 1 : 2;
    for (int rt = 0; rt < nrt; rt++) {
        const int drp = ph ? 1 : rt;            // padded row offset: r+1 = i + drp
        const int a   = ph ? 1 : (rt ? 0 : 2);
        for (int ct = 0; ct < nct; ct++) {
            const int dsp = pw ? 1 : ct;
            const int b   = pw ? 1 : (ct ? 0 : 2);
            const int ab  = a * 3 + b;
            const __hip_bfloat16* A0 =
                xp + (((size_t)(n * 65 + i0 + drp)) * 65 + m0j + dsp) * 512 + klane;
            const __hip_bfloat16* A1 = A0 + (size_t)65 * 512;
            const __hip_bfloat16* B0 =
                wp + ((size_t)(ab * 256 + o0 + m0j)) * 512 + klane;
            const __hip_bfloat16* B1 = B0 + (size_t)64 * 512;

            for (int c0 = 0; c0 < 512; c0 += 32) {
                __syncthreads();
                gl_lds16(A0 + c0, la0);
                gl_lds16(A1 + c0, la1);
                gl_lds16(B0 + c0, lb0);
                gl_lds16(B1 + c0, lb1);
                __syncthreads();
                short8 af[4], bv[4];
#pragma unroll
                for (int fm = 0; fm < 4; fm++)
                    af[fm] = *(const short8*)(lA + ((wm * 64 + fm * 16 + lrow) * 32 + quad * 8));
#pragma unroll
                for (int fn = 0; fn < 4; fn++)
                    bv[fn] = *(const short8*)(lB + ((wn * 64 + fn * 16 + lrow) * 32 + quad * 8));
#pragma unroll
                for (int fm = 0; fm < 4; fm++)
#pragma unroll
                    for (int fn = 0; fn < 4; fn++)
                        acc[fm][fn] = __builtin_amdgcn_mfma_f32_16x16x32_bf16(
                            af[fm], bv[fn], acc[fm][fn], 0, 0, 0);
            }
        }
    }

    // epilogue: D row=(quad*4+reg) -> j, col=lrow -> o ; 4 consecutive j per lane
#pragma unroll
    for (int fm = 0; fm < 4; fm++) {
        int j0 = fm * 16 + quad * 4;
#pragma unroll
        for (int fn = 0; fn < 4; fn++) {
            int o = o0 + wn * 64 + fn * 16 + lrow;
            union { ushort4 v; __hip_bfloat16 h[4]; } u;
#pragma unroll
            for (int r = 0; r < 4; r++) u.h[r] = __float2bfloat16(acc[fm][fn][r]);
            *(ushort4*)(yp + (((size_t)(p * 4096 + n * 256 + o)) << 12) +
                        ((i0 + wm) << 6) + j0) = u.v;
        }
    }
}

// ---------------------------------------------------------------- FIR -------
// one block per (n,o) plane. Stage 4 parity planes (32KB) in LDS via short8,
// each thread computes a quad-pair (2 out rows x 4 out cols) per iteration.
__device__ __forceinline__ float bf_lo(unsigned u) { return __uint_as_float(u << 16); }
__device__ __forceinline__ float bf_hi(unsigned u) { return __uint_as_float(u & 0xffff0000u); }

__global__ __launch_bounds__(256) void fir_kernel(
    const __hip_bfloat16* __restrict__ yp, float* __restrict__ out) {
    const int no  = blockIdx.x;          // n*256 + o
    const int tid = (int)threadIdx.x;

    __shared__ __align__(16) unsigned short ylds[4 * 64 * 64];  // [q][ih][jw], 32KB

    // stage: 4 planes x 4096 bf16 = 2048 short8 chunks, fully coalesced
    const unsigned short* ysrc = (const unsigned short*)yp;
#pragma unroll
    for (int k = 0; k < 8; k++) {
        int chunk = k * 256 + tid;           // 0..2047
        int q   = chunk >> 9;                // 0..3
        int off = (chunk & 511) << 3;        // element offset in plane
        *(short8*)(ylds + q * 4096 + off) =
            *(const short8*)(ysrc + (((size_t)(q * 4096 + no)) << 12) + off);
    }
    __syncthreads();

    const unsigned* yw = (const unsigned*)ylds;  // word view: [q][ih][w], w=0..31

    const int qp = tid & 31;     // quad-pair: covers out cols 4qp..4qp+3
    const int iw = tid >> 5;     // 0..7

    // weight of plane-parity q, offset k, for output sub-parity e
    const float rw[2][2][2] = {{{0.4f, 0.4f}, {1.2f, 0.f}},
                               {{0.f, 1.2f}, {0.4f, 0.4f}}};  // [e][q][k]

    for (int s = 0; s < 8; s++) {
        const int I = s * 8 + iw;            // 0..63 (out rows 2I, 2I+1)

        // Y3[ph][pw][k][m]: cols {2qp-1, 2qp, 2qp+1} of plane (ph,pw), row I-1+k
        float Y3[2][2][2][3];
#pragma unroll
        for (int q = 0; q < 4; q++) {
            int phh = q >> 1, pww = q & 1;
#pragma unroll
            for (int k = 0; k < 2; k++) {
                int ih = I - 1 + k;
                float c0 = 0.f, c1 = 0.f, c2 = 0.f;
                if (ih >= 0) {
                    const unsigned* row = yw + (q * 64 + ih) * 32;
                    unsigned wb = row[qp];
                    c1 = bf_lo(wb);
                    c2 = bf_hi(wb);
                    if (qp > 0) c0 = bf_hi(row[qp - 1]);
                }
                Y3[phh][pww][k][0] = c0;
                Y3[phh][pww][k][1] = c1;
                Y3[phh][pww][k][2] = c2;
            }
        }

        float res[2][4];
#pragma unroll
        for (int t = 0; t < 2; t++) {        // quad t: J = 2qp+t, taps cols {t, t+1}
            float cs[2][2][2];               // [ph][k][ew]
#pragma unroll
            for (int phh = 0; phh < 2; phh++)
#pragma unroll
                for (int k = 0; k < 2; k++)
#pragma unroll
                    for (int ew = 0; ew < 2; ew++) {
                        float sv = 0.f;
#pragma unroll
                        for (int pww = 0; pww < 2; pww++)
#pragma unroll
                            for (int l = 0; l < 2; l++)
                                sv += rw[ew][pww][l] * Y3[phh][pww][k][t + l];
                        cs[phh][k][ew] = sv;
                    }
#pragma unroll
            for (int eh = 0; eh < 2; eh++)
#pragma unroll
                for (int ew = 0; ew < 2; ew++) {
                    float sv = 0.f;
#pragma unroll
                    for (int phh = 0; phh < 2; phh++)
#pragma unroll
                        for (int k = 0; k < 2; k++)
                            sv += rw[eh][phh][k] * cs[phh][k][ew];
                    res[eh][t * 2 + ew] = sv;
                }
        }

        size_t base = ((size_t)no << 14) + ((size_t)(2 * I) << 7) + 4 * qp;
        float4v v0 = {res[0][0], res[0][1], res[0][2], res[0][3]};
        float4v v1 = {res[1][0], res[1][1], res[1][2], res[1][3]};
        *(float4v*)(out + base)       = v0;
        *(float4v*)(out + base + 128) = v1;
    }
}

// ------------------------------------------------- fallback (ws too small) --
__global__ __launch_bounds__(256) void fused_direct_kernel(
    const float* __restrict__ x, const float* __restrict__ w,
    float* __restrict__ out) {
    int idx = blockIdx.x * 256 + (int)threadIdx.x;
    int w_ = idx & 127, h = (idx >> 7) & 127, no = idx >> 14;
    int o = no & 255, n = no >> 8;
    int I = h >> 1, J = w_ >> 1;
    const float fr0 = 0.4f, fr1 = 1.2f, fr2 = 0.4f;
    float gh[3][3]; int rh[3]; int nh;
    if ((h & 1) == 0) {
        nh = 3;
        rh[0] = I - 2; gh[0][0] = 0.f; gh[0][1] = 0.f; gh[0][2] = fr0;
        rh[1] = I - 1; gh[1][0] = fr0; gh[1][1] = fr1; gh[1][2] = fr2;
        rh[2] = I;     gh[2][0] = fr2; gh[2][1] = 0.f; gh[2][2] = 0.f;
    } else {
        nh = 2;
        rh[0] = I - 1; gh[0][0] = 0.f; gh[0][1] = fr0; gh[0][2] = fr1;
        rh[1] = I;     gh[1][0] = fr1; gh[1][1] = fr2; gh[1][2] = 0.f;
    }
    float gw[3][3]; int cw[3]; int nw;
    if ((w_ & 1) == 0) {
        nw = 3;
        cw[0] = J - 2; gw[0][0] = 0.f; gw[0][1] = 0.f; gw[0][2] = fr0;
        cw[1] = J - 1; gw[1][0] = fr0; gw[1][1] = fr1; gw[1][2] = fr2;
        cw[2] = J;     gw[2][0] = fr2; gw[2][1] = 0.f; gw[2][2] = 0.f;
    } else {
        nw = 2;
        cw[0] = J - 1; gw[0][0] = 0.f; gw[0][1] = fr0; gw[0][2] = fr1;
        cw[1] = J;     gw[1][0] = fr1; gw[1][1] = fr2; gw[1][2] = 0.f;
    }
    float acc = 0.f;
    for (int c = 0; c < 512; c++) {
        const float* xb = x + ((size_t)(n * 512 + c) << 12);
        const float* wb = w + (size_t)(c * 256 + o) * 9;
        float tmp[3][3];
#pragma unroll
        for (int dr = 0; dr < 3; dr++) tmp[dr][0] = tmp[dr][1] = tmp[dr][2] = 0.f;
        for (int dr = 0; dr < nh; dr++) {
            int r = rh[dr]; if (r < 0) continue;
            for (int ds = 0; ds < nw; ds++) {
                int s = cw[ds]; if (s < 0) continue;
                float xv = xb[(r << 6) + s];
                tmp[dr][0] += gw[ds][0] * xv;
                tmp[dr][1] += gw[ds][1] * xv;
                tmp[dr][2] += gw[ds][2] * xv;
            }
        }
#pragma unroll
        for (int a = 0; a < 3; a++) {
            float xg0 = 0.f, xg1 = 0.f, xg2 = 0.f;
            for (int dr = 0; dr < nh; dr++) {
                float g = gh[dr][a];
                xg0 += g * tmp[dr][0]; xg1 += g * tmp[dr][1]; xg2 += g * tmp[dr][2];
            }
            acc += xg0 * wb[a * 3] + xg1 * wb[a * 3 + 1] + xg2 * wb[a * 3 + 2];
        }
    }
    out[idx] = acc;
}

// ---------------------------------------------------------------- launch ----
extern "C" void kernel_launch(void* const* d_in, const int* in_sizes, int n_in,
                              void* d_out, int out_size, void* d_ws, size_t ws_size,
                              hipStream_t stream)
{
    (void)in_sizes; (void)n_in; (void)out_size;
    const float* x = (const float*)d_in[0];   // (16,512,64,64)
    const float* w = (const float*)d_in[1];   // (256,512,3,3)
    float* out = (float*)d_out;               // (16,256,128,128)

    const size_t need = (XP_ELEMS + WP_ELEMS + YP_ELEMS) * sizeof(__hip_bfloat16);
    if (ws_size >= need) {
        __hip_bfloat16* xp = (__hip_bfloat16*)d_ws;
        __hip_bfloat16* wp = xp + XP_ELEMS;
        __hip_bfloat16* yp = wp + WP_ELEMS;
        zero_pad_kernel<<<dim3((16 * 65 * 512 + 255) / 256), dim3(256), 0, stream>>>(xp);
        pack_w_kernel<<<dim3((int)(WP_ELEMS / 256)), dim3(256), 0, stream>>>(w, wp);
        pack_x_kernel<<<dim3(64, 16), dim3(256), 0, stream>>>(x, xp);
        mfma_conv_kernel<<<dim3(2, 512, 4), dim3(256), 0, stream>>>(xp, wp, yp);
        fir_kernel<<<dim3(4096), dim3(256), 0, stream>>>(yp, out);
    } else {
        fused_direct_kernel<<<dim3((int)(YP_ELEMS / 256)), dim3(256), 0, stream>>>(x, w, out);
    }
}